// Round 11
// baseline (4809.452 us; speedup 1.0000x reference)
//
#include <hip/hip_runtime.h>
#include <stdint.h>

#define BDIM 64
#define TDIM 512
#define EDIM 512
#define HDIM 512

typedef __attribute__((ext_vector_type(8))) short bf16x8;
typedef __attribute__((ext_vector_type(4))) float f32x4;
typedef __attribute__((ext_vector_type(4))) unsigned int u32x4;
typedef __attribute__((ext_vector_type(4))) unsigned short u16x4;
typedef unsigned long long u64t;

static __device__ __forceinline__ unsigned short f2bf(float f) {
  union { float f; uint32_t u; } c; c.f = f;
  uint32_t u = c.u;
  uint32_t r = u + 0x7fffu + ((u >> 16) & 1u);
  return (unsigned short)(r >> 16);
}
static __device__ __forceinline__ float bf2f(unsigned short s) {
  union { uint32_t u; float f; } c; c.u = ((uint32_t)s) << 16;
  return c.f;
}

// swizzle for 1KB-row tiles (512 bf16 per row)
#define SWZ(row, byteInRow) ((((row)*1024) + (byteInRow)) ^ ((((row)&7))<<4))
// swizzle for 128B-row tiles (64 bf16 per row)
#define SWZA(row, byteInRow) ((((row)*128) + (byteInRow)) ^ ((((row)&7))<<4))

// ---------------- small utility kernels ----------------

__global__ void sentinel_kern(float* out, int n) {
  for (int i = blockIdx.x * blockDim.x + threadIdx.x; i < n; i += gridDim.x * blockDim.x)
    out[i] = -12345.0f;
}

__global__ void conv_w(const float* __restrict__ Wz, const float* __restrict__ Wr,
                       const float* __restrict__ Wh,
                       unsigned short* __restrict__ Wxb, unsigned short* __restrict__ Whb) {
  int idx = blockIdx.x * 256 + threadIdx.x;
  if (idx >= 3 * 512 * 1024) return;
  int g = idx >> 19;
  int rem = idx & 524287;
  int j = rem >> 10, k = rem & 1023;
  const float* W = (g == 0) ? Wz : (g == 1) ? Wr : Wh;
  unsigned short b = f2bf(W[(size_t)j * 1024 + k]);
  if (k < 512) Wxb[((size_t)g * 512 + j) * 512 + k] = b;
  else         Whb[((size_t)g * 512 + j) * 512 + (k - 512)] = b;
}

__global__ void conv_x(const float* __restrict__ x, unsigned short* __restrict__ xb, int n4) {
  for (int i = blockIdx.x * blockDim.x + threadIdx.x; i < n4; i += gridDim.x * blockDim.x) {
    f32x4 v = ((const f32x4*)x)[i];
    u16x4 o;
    o[0] = f2bf(v[0]); o[1] = f2bf(v[1]); o[2] = f2bf(v[2]); o[3] = f2bf(v[3]);
    ((u16x4*)xb)[i] = o;
  }
}

__global__ void add_out(float* __restrict__ out, const float* __restrict__ Hb, int n4) {
  for (int i = blockIdx.x * blockDim.x + threadIdx.x; i < n4; i += gridDim.x * blockDim.x) {
    f32x4 a = ((const f32x4*)out)[i];
    f32x4 b = ((const f32x4*)Hb)[i];
    ((f32x4*)out)[i] = a + b;
  }
}

// ---------------- phase A: G = x @ Wx^T + bias (bf16 out) ----------------

__global__ __launch_bounds__(256, 2)
void gru_xproj(const unsigned short* __restrict__ xb,
               const unsigned short* __restrict__ Wxb,
               const float* __restrict__ bz, const float* __restrict__ br,
               const float* __restrict__ bh,
               unsigned short* __restrict__ Gb) {
  __shared__ __align__(16) unsigned short lA[128 * 64];
  __shared__ __align__(16) unsigned short lB[128 * 64];
  const int tid = threadIdx.x;
  const int m0 = blockIdx.x * 128;
  const int n0 = blockIdx.y * 128;
  const int w = tid >> 6, lane = tid & 63, cl = lane & 15, q = lane >> 4;
  const int wr = w >> 1, wc = w & 1;
  f32x4 acc[4][4];
#pragma unroll
  for (int i = 0; i < 4; i++)
#pragma unroll
    for (int j = 0; j < 4; j++) acc[i][j] = (f32x4){0.f, 0.f, 0.f, 0.f};

  for (int ko = 0; ko < 8; ko++) {
    int k0 = ko * 64;
#pragma unroll
    for (int cc = 0; cc < 4; cc++) {
      int qq = tid * 4 + cc;
      int row = qq >> 3, kc = qq & 7;
      u32x4 va = *(const u32x4*)(xb + ((size_t)(m0 + row) * EDIM + k0 + kc * 8));
      *(u32x4*)((char*)lA + SWZA(row, kc * 16)) = va;
      u32x4 vb = *(const u32x4*)(Wxb + ((size_t)(n0 + row) * EDIM + k0 + kc * 8));
      *(u32x4*)((char*)lB + SWZA(row, kc * 16)) = vb;
    }
    __syncthreads();
#pragma unroll
    for (int ks = 0; ks < 2; ks++) {
      bf16x8 af[4], bfv[4];
#pragma unroll
      for (int i = 0; i < 4; i++) {
        int rl = wr * 64 + i * 16 + cl;
        af[i] = *(const bf16x8*)((char*)lA + SWZA(rl, ks * 64 + q * 16));
      }
#pragma unroll
      for (int j = 0; j < 4; j++) {
        int rl = wc * 64 + j * 16 + cl;
        bfv[j] = *(const bf16x8*)((char*)lB + SWZA(rl, ks * 64 + q * 16));
      }
#pragma unroll
      for (int i = 0; i < 4; i++)
#pragma unroll
        for (int j = 0; j < 4; j++)
          acc[i][j] = __builtin_amdgcn_mfma_f32_16x16x32_bf16(af[i], bfv[j], acc[i][j], 0, 0, 0);
    }
    __syncthreads();
  }
  const int g = n0 >> 9;
  const float* bias = (g == 0) ? bz : (g == 1) ? br : bh;
#pragma unroll
  for (int i = 0; i < 4; i++) {
#pragma unroll
    for (int j = 0; j < 4; j++) {
      int n = n0 + wc * 64 + j * 16 + cl;
      float bv = bias[n & 511];
#pragma unroll
      for (int ii = 0; ii < 4; ii++) {
        int m = m0 + wr * 64 + i * 16 + q * 4 + ii;
        Gb[(size_t)m * 1536 + n] = f2bf(acc[i][j][ii] + bv);
      }
    }
  }
}

// ---------------- persistent recurrence: dual-direction pipelined ----------
// 64 wgs: bg = bid&3 (16 batches), cg = bid>>2 (32 cols). Each wg runs BOTH
// directions, interleaved, sharing the LDS weight tiles. Rendezvous groups:
// (dir, bg) -> 8 groups x 16 wgs, counters ctr_rh / ctr_h per group.
// Counter targets are 16*(s+1): 16 wgs/group increment once per step (this was
// the R10 bug — target was missing the x16).

__global__ __launch_bounds__(256, 1)
void gru_persist(const unsigned short* __restrict__ Gb,
                 const float* __restrict__ h0,
                 unsigned short* __restrict__ Hst,    // [2*64][512] bf16
                 unsigned short* __restrict__ RHst,   // [2*64][512] bf16
                 unsigned int*   __restrict__ ctrs,   // 16 x 128B lines
                 float* __restrict__ outp,
                 float* __restrict__ Hb,
                 const unsigned short* __restrict__ Whb) {
  __shared__ __align__(16) unsigned short lds_w[6 * 16 * 512];    // 96KB
  __shared__ __align__(16) unsigned short lds_st[2][16 * 512];    // 32KB (ah->arh reuse)
  __shared__ float lds_hp[2][16 * 32];                             // 4KB

  const int tid = threadIdx.x;
  const int bid = blockIdx.x;
  const int bg = bid & 3;
  const int cg = bid >> 2;
  const int j0 = cg * 32;
  const int w = tid >> 6;
  const int lane = tid & 63;
  const int c = lane & 15;
  const int q = lane >> 4;
  const int sub = w & 1;
  const int jn = j0 + sub * 16 + c;
  const int gateA = (w < 2) ? 0 : 1;

  unsigned int* ctr_rh[2] = { &ctrs[(0 * 4 + bg) * 32], &ctrs[(4 + bg) * 32] };
  unsigned int* ctr_h[2]  = { &ctrs[(8 + 0 * 4 + bg) * 32], &ctrs[(8 + 4 + bg) * 32] };

  // ---- one-time: weight LDS tiles (nt = gate*2+sub) ----
  for (int qk = tid; qk < 6144; qk += 256) {
    int nt = qk >> 10;
    int cin = qk & 1023;
    int col = cin & 15;
    int kc = cin >> 4;
    int g = nt >> 1, sub2 = nt & 1;
    int jglob = j0 + sub2 * 16 + col;
    u32x4 v = *(const u32x4*)(Whb + (((size_t)g * 512 + jglob) * 512 + kc * 8));
    *(u32x4*)((char*)lds_w + nt * 16384 + SWZ(col, kc * 16)) = v;
  }

  // ---- init hprev + publish h0 for both dirs ----
#pragma unroll
  for (int d = 0; d < 2; d++) {
#pragma unroll
    for (int ii = 0; ii < 2; ii++) {
      int idx = tid * 2 + ii;
      int row = idx >> 5, jl = idx & 31;
      int b = bg * 16 + row, j = j0 + jl;
      float v = h0[(size_t)b * HDIM + j];
      lds_hp[d][row * 32 + jl] = v;
      __hip_atomic_store(&Hst[((size_t)d * 64 + b) * 512 + j], f2bf(v),
                         __ATOMIC_RELAXED, __HIP_MEMORY_SCOPE_AGENT);
    }
  }
  asm volatile("s_waitcnt vmcnt(0)" ::: "memory");
  __syncthreads();
  if (tid == 0) {
    __hip_atomic_fetch_add(ctr_h[0], 1u, __ATOMIC_RELAXED, __HIP_MEMORY_SCOPE_AGENT);
    __hip_atomic_fetch_add(ctr_h[1], 1u, __ATOMIC_RELAXED, __HIP_MEMORY_SCOPE_AGENT);
  }

  // ---- helpers ----
  auto garrive = [&](unsigned int* ctr) {
    asm volatile("s_waitcnt vmcnt(0)" ::: "memory");
    __syncthreads();
    if (tid == 0)
      __hip_atomic_fetch_add(ctr, 1u, __ATOMIC_RELAXED, __HIP_MEMORY_SCOPE_AGENT);
  };
  auto gwait = [&](unsigned int* ctr, unsigned tgt) {
    if (tid == 0)
      while (__hip_atomic_load(ctr, __ATOMIC_RELAXED, __HIP_MEMORY_SCOPE_AGENT) < tgt) {}
    __syncthreads();
  };
  auto stage = [&](const unsigned short* srcArr, int d, unsigned short* dstLds) {
    int row = tid >> 4, seg = tid & 15;
    const char* srcb = (const char*)srcArr + (size_t)(d * 64 + bg * 16 + row) * 1024 + seg * 8;
    u64t v[8];
#pragma unroll
    for (int i = 0; i < 8; i++)
      v[i] = __hip_atomic_load((const u64t*)(srcb + i * 128),
                               __ATOMIC_RELAXED, __HIP_MEMORY_SCOPE_AGENT);
    char* dst = (char*)dstLds;
#pragma unroll
    for (int i = 0; i < 8; i++)
      *(u64t*)(dst + SWZ(row, seg * 8 + i * 128)) = v[i];
  };
  auto mfma16 = [&](const char* ab, const char* wb) -> f32x4 {
    f32x4 a0 = (f32x4){0.f,0.f,0.f,0.f}, a1 = (f32x4){0.f,0.f,0.f,0.f};
    f32x4 a2 = (f32x4){0.f,0.f,0.f,0.f}, a3 = (f32x4){0.f,0.f,0.f,0.f};
#pragma unroll
    for (int ks = 0; ks < 4; ks++) {
#pragma unroll
      for (int p = 0; p < 4; p++) {
        int kb = (ks * 4 + p) * 64 + q * 16;
        bf16x8 af = *(const bf16x8*)(ab + SWZ(c, kb));
        bf16x8 bfv = *(const bf16x8*)(wb + SWZ(c, kb));
        if (p == 0) a0 = __builtin_amdgcn_mfma_f32_16x16x32_bf16(af, bfv, a0, 0, 0, 0);
        else if (p == 1) a1 = __builtin_amdgcn_mfma_f32_16x16x32_bf16(af, bfv, a1, 0, 0, 0);
        else if (p == 2) a2 = __builtin_amdgcn_mfma_f32_16x16x32_bf16(af, bfv, a2, 0, 0, 0);
        else a3 = __builtin_amdgcn_mfma_f32_16x16x32_bf16(af, bfv, a3, 0, 0, 0);
      }
    }
    return (a0 + a1) + (a2 + a3);
  };
  // P1: z (w0,1 -> zreg) and r + packed rh publish (w2,3)
  auto P1 = [&](int d, const char* ab, const f32x4& gA, f32x4& zreg_s) {
    f32x4 acc = mfma16(ab, (const char*)lds_w + w * 16384);
    if (w < 2) {
#pragma unroll
      for (int i = 0; i < 4; i++) {
        float pre = acc[i] + gA[i];
        pre = fminf(fmaxf(pre, -30.f), 30.f);
        zreg_s[i] = 1.f / (1.f + __expf(-pre));
      }
    } else {
      float rhv[4];
#pragma unroll
      for (int i = 0; i < 4; i++) {
        int row = q * 4 + i;
        float pre = acc[i] + gA[i];
        pre = fminf(fmaxf(pre, -30.f), 30.f);
        float sg = 1.f / (1.f + __expf(-pre));
        rhv[i] = sg * lds_hp[d][row * 32 + sub * 16 + c];
      }
#pragma unroll
      for (int i = 0; i < 4; i++) {
        float oth = __shfl_xor(rhv[i], 1);
        if (!(c & 1)) {
          int b = bg * 16 + q * 4 + i;
          unsigned int pk = (unsigned int)f2bf(rhv[i]) | ((unsigned int)f2bf(oth) << 16);
          __hip_atomic_store(
              (unsigned int*)&RHst[(size_t)(d * 64 + b) * 512 + jn],
              pk, __ATOMIC_RELAXED, __HIP_MEMORY_SCOPE_AGENT);
        }
      }
    }
  };
  // P2: h~ + blend + outp + packed h publish (w0,1)
  auto P2 = [&](int d, const char* ab, const f32x4& gC, const f32x4& zreg_s,
                float* op, int t) {
    if (w < 2) {
      f32x4 acc2 = mfma16(ab, (const char*)lds_w + (4 + sub) * 16384);
      float hn[4];
#pragma unroll
      for (int i = 0; i < 4; i++) {
        int row = q * 4 + i;
        int b = bg * 16 + row;
        float pre = acc2[i] + gC[i];
        pre = fminf(fmaxf(pre, -15.f), 15.f);
        float e2 = __expf(2.f * pre);
        float th = (e2 - 1.f) / (e2 + 1.f);
        float hp = lds_hp[d][row * 32 + sub * 16 + c];
        float z = zreg_s[i];
        hn[i] = hp + z * (th - hp);
        op[((size_t)b * TDIM + t) * HDIM + jn] = hn[i];
        lds_hp[d][row * 32 + sub * 16 + c] = hn[i];
      }
#pragma unroll
      for (int i = 0; i < 4; i++) {
        float oth = __shfl_xor(hn[i], 1);
        if (!(c & 1)) {
          int b = bg * 16 + q * 4 + i;
          unsigned int pk = (unsigned int)f2bf(hn[i]) | ((unsigned int)f2bf(oth) << 16);
          __hip_atomic_store(
              (unsigned int*)&Hst[(size_t)(d * 64 + b) * 512 + jn],
              pk, __ATOMIC_RELAXED, __HIP_MEMORY_SCOPE_AGENT);
        }
      }
    }
  };

  f32x4 zreg_f, zreg_b;

  for (int s = 0; s < TDIM; s++) {
    const int t_f = s;
    const int t_b = TDIM - 1 - s;
    const unsigned tgt = 16u * (unsigned)(s + 1);   // 16 wgs/group per step

    // ---- G prefetch for both streams (plain cached loads) ----
    f32x4 gA_f, gC_f, gA_b, gC_b;
#pragma unroll
    for (int i = 0; i < 4; i++) {
      int b = bg * 16 + q * 4 + i;
      size_t mf = ((size_t)b * TDIM + t_f) * 3;
      size_t mb = ((size_t)b * TDIM + t_b) * 3;
      gA_f[i] = bf2f(Gb[(mf + gateA) * HDIM + jn]);
      gA_b[i] = bf2f(Gb[(mb + gateA) * HDIM + jn]);
      if (w < 2) {
        gC_f[i] = bf2f(Gb[(mf + 2) * HDIM + jn]);
        gC_b[i] = bf2f(Gb[(mb + 2) * HDIM + jn]);
      }
    }

    // ===== stream F: first half =====
    gwait(ctr_h[0], tgt);
    stage(Hst, 0, lds_st[0]);
    __syncthreads();
    P1(0, (const char*)lds_st[0], gA_f, zreg_f);
    garrive(ctr_rh[0]);

    // ===== stream B: first half (hides F's rh rendezvous) =====
    gwait(ctr_h[1], tgt);
    stage(Hst, 1, lds_st[1]);
    __syncthreads();
    P1(1, (const char*)lds_st[1], gA_b, zreg_b);
    garrive(ctr_rh[1]);

    // ===== stream F: second half =====
    gwait(ctr_rh[0], tgt);
    stage(RHst, 0, lds_st[0]);
    __syncthreads();
    P2(0, (const char*)lds_st[0], gC_f, zreg_f, outp, t_f);
    garrive(ctr_h[0]);

    // ===== stream B: second half (hides F's h rendezvous for next iter) =====
    gwait(ctr_rh[1], tgt);
    stage(RHst, 1, lds_st[1]);
    __syncthreads();
    P2(1, (const char*)lds_st[1], gC_b, zreg_b, Hb, t_b);
    garrive(ctr_h[1]);
  }
}

// ---------------- host ----------------

extern "C" void kernel_launch(void* const* d_in, const int* in_sizes, int n_in,
                              void* d_out, int out_size, void* d_ws, size_t ws_size,
                              hipStream_t stream) {
  (void)in_sizes; (void)n_in;
  const float* x  = (const float*)d_in[0];
  const float* h0 = (const float*)d_in[1];
  const float* Wz = (const float*)d_in[2];
  const float* bz = (const float*)d_in[3];
  const float* Wr = (const float*)d_in[4];
  const float* br = (const float*)d_in[5];
  const float* Wh = (const float*)d_in[6];
  const float* bh = (const float*)d_in[7];
  float* outp = (float*)d_out;

  const size_t szG    = (size_t)32768 * 1536 * 2;       // bf16 G
  const size_t szXb   = (size_t)BDIM * TDIM * EDIM * 2;
  const size_t szW    = (size_t)3 * 512 * 512 * 2;
  const size_t szHb   = (size_t)BDIM * TDIM * HDIM * 4;
  const size_t szHst  = (size_t)2 * 64 * 512 * 2;
  const size_t szFl   = 4096;
  const size_t fixed  = szXb + 2 * szW + szHb + 2 * szHst + szFl + 16384;

  if (ws_size < fixed + szG) {
    sentinel_kern<<<256, 256, 0, stream>>>(outp, out_size);
    return;
  }

  size_t off = 0;
  char* base = (char*)d_ws;
  auto alloc = [&](size_t sz) { char* p = base + off; off = (off + sz + 255) & ~(size_t)255; return p; };
  unsigned short* Gb   = (unsigned short*)alloc(szG);
  unsigned short* xb   = (unsigned short*)alloc(szXb);
  unsigned short* Wxb  = (unsigned short*)alloc(szW);
  unsigned short* Whb  = (unsigned short*)alloc(szW);
  float*          Hbuf = (float*)alloc(szHb);
  unsigned short* Hst  = (unsigned short*)alloc(szHst);
  unsigned short* RHst = (unsigned short*)alloc(szHst);
  unsigned int*   ctrs = (unsigned int*)alloc(szFl);

  hipMemsetAsync(ctrs, 0, szFl, stream);
  conv_w<<<(3 * 512 * 1024 + 255) / 256, 256, 0, stream>>>(Wz, Wr, Wh, Wxb, Whb);
  conv_x<<<2048, 256, 0, stream>>>(x, xb, (BDIM * TDIM * EDIM) / 4);
  gru_xproj<<<dim3(256, 12), 256, 0, stream>>>(xb, Wxb, bz, br, bh, Gb);
  gru_persist<<<64, 256, 0, stream>>>(Gb, h0, Hst, RHst, ctrs, outp, Hbuf, Whb);
  add_out<<<2048, 256, 0, stream>>>(outp, Hbuf, (BDIM * TDIM * HDIM) / 4);
  hipMemcpyAsync(outp + (size_t)BDIM * TDIM * HDIM, h0,
                 (size_t)BDIM * HDIM * sizeof(float), hipMemcpyDeviceToDevice, stream);
}

// Round 12
// 2873.638 us; speedup vs baseline: 1.6736x; 1.6736x over previous
//
#include <hip/hip_runtime.h>
#include <stdint.h>

#define BDIM 64
#define TDIM 512
#define EDIM 512
#define HDIM 512

typedef __attribute__((ext_vector_type(8))) short bf16x8;
typedef __attribute__((ext_vector_type(4))) float f32x4;
typedef __attribute__((ext_vector_type(4))) unsigned int u32x4;
typedef __attribute__((ext_vector_type(4))) unsigned short u16x4;
typedef unsigned long long u64t;

static __device__ __forceinline__ unsigned short f2bf(float f) {
  union { float f; uint32_t u; } c; c.f = f;
  uint32_t u = c.u;
  uint32_t r = u + 0x7fffu + ((u >> 16) & 1u);
  return (unsigned short)(r >> 16);
}
static __device__ __forceinline__ float bf2f(unsigned short s) {
  union { uint32_t u; float f; } c; c.u = ((uint32_t)s) << 16;
  return c.f;
}

// swizzle for 1KB-row tiles (512 bf16 per row)
#define SWZ(row, byteInRow) ((((row)*1024) + (byteInRow)) ^ ((((row)&7))<<4))
// swizzle for 128B-row tiles (64 bf16 per row)
#define SWZA(row, byteInRow) ((((row)*128) + (byteInRow)) ^ ((((row)&7))<<4))

// ---------------- small utility kernels ----------------

__global__ void sentinel_kern(float* out, int n) {
  for (int i = blockIdx.x * blockDim.x + threadIdx.x; i < n; i += gridDim.x * blockDim.x)
    out[i] = -12345.0f;
}

__global__ void conv_w(const float* __restrict__ Wz, const float* __restrict__ Wr,
                       const float* __restrict__ Wh,
                       unsigned short* __restrict__ Wxb, unsigned short* __restrict__ Whb) {
  int idx = blockIdx.x * 256 + threadIdx.x;
  if (idx >= 3 * 512 * 1024) return;
  int g = idx >> 19;
  int rem = idx & 524287;
  int j = rem >> 10, k = rem & 1023;
  const float* W = (g == 0) ? Wz : (g == 1) ? Wr : Wh;
  unsigned short b = f2bf(W[(size_t)j * 1024 + k]);
  if (k < 512) Wxb[((size_t)g * 512 + j) * 512 + k] = b;
  else         Whb[((size_t)g * 512 + j) * 512 + (k - 512)] = b;
}

__global__ void conv_x(const float* __restrict__ x, unsigned short* __restrict__ xb, int n4) {
  for (int i = blockIdx.x * blockDim.x + threadIdx.x; i < n4; i += gridDim.x * blockDim.x) {
    f32x4 v = ((const f32x4*)x)[i];
    u16x4 o;
    o[0] = f2bf(v[0]); o[1] = f2bf(v[1]); o[2] = f2bf(v[2]); o[3] = f2bf(v[3]);
    ((u16x4*)xb)[i] = o;
  }
}

__global__ void add_out(float* __restrict__ out, const float* __restrict__ Hb, int n4) {
  for (int i = blockIdx.x * blockDim.x + threadIdx.x; i < n4; i += gridDim.x * blockDim.x) {
    f32x4 a = ((const f32x4*)out)[i];
    f32x4 b = ((const f32x4*)Hb)[i];
    ((f32x4*)out)[i] = a + b;
  }
}

// ---------------- phase A: G = x @ Wx^T + bias (bf16 out) ----------------

__global__ __launch_bounds__(256, 2)
void gru_xproj(const unsigned short* __restrict__ xb,
               const unsigned short* __restrict__ Wxb,
               const float* __restrict__ bz, const float* __restrict__ br,
               const float* __restrict__ bh,
               unsigned short* __restrict__ Gb) {
  __shared__ __align__(16) unsigned short lA[128 * 64];
  __shared__ __align__(16) unsigned short lB[128 * 64];
  const int tid = threadIdx.x;
  const int m0 = blockIdx.x * 128;
  const int n0 = blockIdx.y * 128;
  const int w = tid >> 6, lane = tid & 63, cl = lane & 15, q = lane >> 4;
  const int wr = w >> 1, wc = w & 1;
  f32x4 acc[4][4];
#pragma unroll
  for (int i = 0; i < 4; i++)
#pragma unroll
    for (int j = 0; j < 4; j++) acc[i][j] = (f32x4){0.f, 0.f, 0.f, 0.f};

  for (int ko = 0; ko < 8; ko++) {
    int k0 = ko * 64;
#pragma unroll
    for (int cc = 0; cc < 4; cc++) {
      int qq = tid * 4 + cc;
      int row = qq >> 3, kc = qq & 7;
      u32x4 va = *(const u32x4*)(xb + ((size_t)(m0 + row) * EDIM + k0 + kc * 8));
      *(u32x4*)((char*)lA + SWZA(row, kc * 16)) = va;
      u32x4 vb = *(const u32x4*)(Wxb + ((size_t)(n0 + row) * EDIM + k0 + kc * 8));
      *(u32x4*)((char*)lB + SWZA(row, kc * 16)) = vb;
    }
    __syncthreads();
#pragma unroll
    for (int ks = 0; ks < 2; ks++) {
      bf16x8 af[4], bfv[4];
#pragma unroll
      for (int i = 0; i < 4; i++) {
        int rl = wr * 64 + i * 16 + cl;
        af[i] = *(const bf16x8*)((char*)lA + SWZA(rl, ks * 64 + q * 16));
      }
#pragma unroll
      for (int j = 0; j < 4; j++) {
        int rl = wc * 64 + j * 16 + cl;
        bfv[j] = *(const bf16x8*)((char*)lB + SWZA(rl, ks * 64 + q * 16));
      }
#pragma unroll
      for (int i = 0; i < 4; i++)
#pragma unroll
        for (int j = 0; j < 4; j++)
          acc[i][j] = __builtin_amdgcn_mfma_f32_16x16x32_bf16(af[i], bfv[j], acc[i][j], 0, 0, 0);
    }
    __syncthreads();
  }
  const int g = n0 >> 9;
  const float* bias = (g == 0) ? bz : (g == 1) ? br : bh;
#pragma unroll
  for (int i = 0; i < 4; i++) {
#pragma unroll
    for (int j = 0; j < 4; j++) {
      int n = n0 + wc * 64 + j * 16 + cl;
      float bv = bias[n & 511];
#pragma unroll
      for (int ii = 0; ii < 4; ii++) {
        int m = m0 + wr * 64 + i * 16 + q * 4 + ii;
        Gb[(size_t)m * 1536 + n] = f2bf(acc[i][j][ii] + bv);
      }
    }
  }
}

// ---------------- persistent bidirectional recurrence (R9 + decontended sync)
// 128 wgs: gid = bid&7 (dir = gid>>2, bg = gid&3); cg = bid>>3, cols j0=cg*32.
// vs R9 (2.90 ms): (1) contended fetch_add counter replaced by per-wg 128B
// flag lines (plain monotone stores) + wave0 16-lane poll with s_sleep;
// (2) outp stores moved after the h-flag store (drain deferred into next poll).

__global__ __launch_bounds__(256, 1)
void gru_persist(const unsigned short* __restrict__ Gb,
                 const float* __restrict__ h0,
                 unsigned short* __restrict__ Hst,    // [2*64][512] bf16
                 unsigned short* __restrict__ RHst,   // [2*64][512] bf16
                 unsigned int*   __restrict__ flags,  // [2][8][16] x 128B lines
                 float* __restrict__ outp,
                 float* __restrict__ Hb,
                 const unsigned short* __restrict__ Whb) {
  __shared__ __align__(16) unsigned short lds_w[6 * 16 * 512];   // 96KB
  __shared__ __align__(16) unsigned short lds_ah[16 * 512];      // 16KB
  __shared__ __align__(16) unsigned short lds_arh[16 * 512];     // 16KB
  __shared__ float lds_hprev[16 * 32];                            // 2KB

  const int tid = threadIdx.x;
  const int bid = blockIdx.x;
  const int gid = bid & 7;
  const int cg = bid >> 3;
  const int dir = gid >> 2;
  const int bg = gid & 3;
  const int j0 = cg * 32;
  const int w = tid >> 6;
  const int lane = tid & 63;
  const int c = lane & 15;
  const int q = lane >> 4;

  // flag lines: fh = flags[0][gid][cg], frh = flags[1][gid][cg]; 32 uints = 128B
  unsigned int* fh_base  = flags + gid * 16 * 32;
  unsigned int* frh_base = flags + (128 + gid * 16) * 32;
  unsigned int* fh_own   = fh_base + cg * 32;
  unsigned int* frh_own  = frh_base + cg * 32;

  // ---- one-time: weight LDS tiles (nt = gate*2+sub) ----
  for (int qk = tid; qk < 6144; qk += 256) {
    int nt = qk >> 10;
    int cin = qk & 1023;
    int col = cin & 15;
    int kc = cin >> 4;
    int g = nt >> 1, sub2 = nt & 1;
    int jglob = j0 + sub2 * 16 + col;
    u32x4 v = *(const u32x4*)(Whb + (((size_t)g * 512 + jglob) * 512 + kc * 8));
    *(u32x4*)((char*)lds_w + nt * 16384 + SWZ(col, kc * 16)) = v;
  }

  // ---- init hprev (fp32, local cols) and Hst ----
#pragma unroll
  for (int ii = 0; ii < 2; ii++) {
    int idx = tid * 2 + ii;
    int row = idx >> 5, jl = idx & 31;
    int b = bg * 16 + row, j = j0 + jl;
    float v = h0[(size_t)b * HDIM + j];
    lds_hprev[row * 32 + jl] = v;
    __hip_atomic_store(&Hst[((size_t)dir * 64 + b) * 512 + j], f2bf(v),
                       __ATOMIC_RELAXED, __HIP_MEMORY_SCOPE_AGENT);
  }
  asm volatile("s_waitcnt vmcnt(0)" ::: "memory");
  __syncthreads();
  if (tid == 0)
    __hip_atomic_store(fh_own, 1u, __ATOMIC_RELAXED, __HIP_MEMORY_SCOPE_AGENT);

  // ---- sync helpers ----
  auto arrive = [&](unsigned int* ownLine, unsigned val) {
    asm volatile("s_waitcnt vmcnt(0)" ::: "memory");
    __syncthreads();
    if (tid == 0)
      __hip_atomic_store(ownLine, val, __ATOMIC_RELAXED, __HIP_MEMORY_SCOPE_AGENT);
  };
  auto wait16 = [&](unsigned int* baseLines, unsigned tgt) {
    if (w == 0) {
      while (true) {
        unsigned fv = tgt;
        if (lane < 16)
          fv = __hip_atomic_load(baseLines + lane * 32,
                                 __ATOMIC_RELAXED, __HIP_MEMORY_SCOPE_AGENT);
        if (__all(fv >= tgt)) break;
        __builtin_amdgcn_s_sleep(1);
      }
    }
    __syncthreads();
  };

  const int sub = w & 1;
  const int jn = j0 + sub * 16 + c;
  const int gateA = (w < 2) ? 0 : 1;

  for (int s = 0; s < TDIM; s++) {
    int t = dir ? (TDIM - 1 - s) : s;
    const unsigned tgt = (unsigned)(s + 1);

    // ---- prefetch G values for this step (plain cached loads) ----
    f32x4 gA, gC;
#pragma unroll
    for (int i = 0; i < 4; i++) {
      int b = bg * 16 + q * 4 + i;
      size_t mrow = (size_t)b * TDIM + t;
      size_t giA = (mrow * 3 + gateA) * HDIM + jn;
      gA[i] = bf2f(Gb[giA]);
      if (w < 2) {
        size_t giC = (mrow * 3 + 2) * HDIM + jn;
        gC[i] = bf2f(Gb[giC]);
      }
    }

    // ---- wait: h(t-1) published by all 16 wgs of the group ----
    wait16(fh_base, tgt);

    // ---- stage A_h: COALESCED atomic loads (16 lanes = 128B contiguous) ----
    {
      int row = tid >> 4, seg = tid & 15;
      const char* srcb = (const char*)Hst +
                         (size_t)(dir * 64 + bg * 16 + row) * 1024 + seg * 8;
      u64t v[8];
#pragma unroll
      for (int i = 0; i < 8; i++)
        v[i] = __hip_atomic_load((const u64t*)(srcb + i * 128),
                                 __ATOMIC_RELAXED, __HIP_MEMORY_SCOPE_AGENT);
      char* dst = (char*)lds_ah;
#pragma unroll
      for (int i = 0; i < 8; i++)
        *(u64t*)(dst + SWZ(row, seg * 8 + i * 128)) = v[i];
    }
    __syncthreads();

    // ---- P1: wave w computes tile nt=w (z: 0,1 ; r: 2,3), K=512 ----
    f32x4 a0 = (f32x4){0.f,0.f,0.f,0.f}, a1 = (f32x4){0.f,0.f,0.f,0.f};
    f32x4 a2 = (f32x4){0.f,0.f,0.f,0.f}, a3 = (f32x4){0.f,0.f,0.f,0.f};
    {
      const char* wb = (const char*)lds_w + w * 16384;
      const char* ab = (const char*)lds_ah;
#pragma unroll
      for (int ks = 0; ks < 4; ks++) {
#pragma unroll
        for (int p = 0; p < 4; p++) {
          int kb = (ks * 4 + p) * 64 + q * 16;
          bf16x8 af = *(const bf16x8*)(ab + SWZ(c, kb));
          bf16x8 bfv = *(const bf16x8*)(wb + SWZ(c, kb));
          if (p == 0) a0 = __builtin_amdgcn_mfma_f32_16x16x32_bf16(af, bfv, a0, 0, 0, 0);
          else if (p == 1) a1 = __builtin_amdgcn_mfma_f32_16x16x32_bf16(af, bfv, a1, 0, 0, 0);
          else if (p == 2) a2 = __builtin_amdgcn_mfma_f32_16x16x32_bf16(af, bfv, a2, 0, 0, 0);
          else a3 = __builtin_amdgcn_mfma_f32_16x16x32_bf16(af, bfv, a3, 0, 0, 0);
        }
      }
    }
    f32x4 acc = (a0 + a1) + (a2 + a3);
    f32x4 zreg;
    if (w < 2) {
#pragma unroll
      for (int i = 0; i < 4; i++) {
        float pre = acc[i] + gA[i];
        pre = fminf(fmaxf(pre, -30.f), 30.f);
        zreg[i] = 1.f / (1.f + __expf(-pre));
      }
    } else {
      // r pointwise + PACKED publish of r*h (4B stores by even-c lanes)
      float rhv[4];
#pragma unroll
      for (int i = 0; i < 4; i++) {
        int row = q * 4 + i;
        float pre = acc[i] + gA[i];
        pre = fminf(fmaxf(pre, -30.f), 30.f);
        float sg = 1.f / (1.f + __expf(-pre));
        rhv[i] = sg * lds_hprev[row * 32 + sub * 16 + c];
      }
#pragma unroll
      for (int i = 0; i < 4; i++) {
        float oth = __shfl_xor(rhv[i], 1);
        if (!(c & 1)) {
          int b = bg * 16 + q * 4 + i;
          unsigned int pk = (unsigned int)f2bf(rhv[i]) | ((unsigned int)f2bf(oth) << 16);
          __hip_atomic_store(
              (unsigned int*)&RHst[(size_t)(dir * 64 + b) * 512 + jn],
              pk, __ATOMIC_RELAXED, __HIP_MEMORY_SCOPE_AGENT);
        }
      }
    }
    arrive(frh_own, tgt);   // r*h published

    // ---- wait: r*h published by all 16 wgs ----
    wait16(frh_base, tgt);

    // ---- stage A_rh: COALESCED atomic loads ----
    {
      int row = tid >> 4, seg = tid & 15;
      const char* srcb = (const char*)RHst +
                         (size_t)(dir * 64 + bg * 16 + row) * 1024 + seg * 8;
      u64t v[8];
#pragma unroll
      for (int i = 0; i < 8; i++)
        v[i] = __hip_atomic_load((const u64t*)(srcb + i * 128),
                                 __ATOMIC_RELAXED, __HIP_MEMORY_SCOPE_AGENT);
      char* dst = (char*)lds_arh;
#pragma unroll
      for (int i = 0; i < 8; i++)
        *(u64t*)(dst + SWZ(row, seg * 8 + i * 128)) = v[i];
    }
    __syncthreads();

    // ---- P2: waves 0,1 compute h~ tiles (nt = 4+sub), blend, publish ----
    float hn[4];
    if (w < 2) {
      f32x4 b0 = (f32x4){0.f,0.f,0.f,0.f}, b1 = (f32x4){0.f,0.f,0.f,0.f};
      f32x4 b2 = (f32x4){0.f,0.f,0.f,0.f}, b3 = (f32x4){0.f,0.f,0.f,0.f};
      const char* wb = (const char*)lds_w + (4 + sub) * 16384;
      const char* ab = (const char*)lds_arh;
#pragma unroll
      for (int ks = 0; ks < 4; ks++) {
#pragma unroll
        for (int p = 0; p < 4; p++) {
          int kb = (ks * 4 + p) * 64 + q * 16;
          bf16x8 af = *(const bf16x8*)(ab + SWZ(c, kb));
          bf16x8 bfv = *(const bf16x8*)(wb + SWZ(c, kb));
          if (p == 0) b0 = __builtin_amdgcn_mfma_f32_16x16x32_bf16(af, bfv, b0, 0, 0, 0);
          else if (p == 1) b1 = __builtin_amdgcn_mfma_f32_16x16x32_bf16(af, bfv, b1, 0, 0, 0);
          else if (p == 2) b2 = __builtin_amdgcn_mfma_f32_16x16x32_bf16(af, bfv, b2, 0, 0, 0);
          else b3 = __builtin_amdgcn_mfma_f32_16x16x32_bf16(af, bfv, b3, 0, 0, 0);
        }
      }
      f32x4 acc2 = (b0 + b1) + (b2 + b3);
#pragma unroll
      for (int i = 0; i < 4; i++) {
        int row = q * 4 + i;
        float pre = acc2[i] + gC[i];
        pre = fminf(fmaxf(pre, -15.f), 15.f);
        float e2 = __expf(2.f * pre);
        float th = (e2 - 1.f) / (e2 + 1.f);
        float hp = lds_hprev[row * 32 + sub * 16 + c];
        float z = zreg[i];
        hn[i] = hp + z * (th - hp);
        lds_hprev[row * 32 + sub * 16 + c] = hn[i];
      }
      // PACKED publish of h(t)
#pragma unroll
      for (int i = 0; i < 4; i++) {
        float oth = __shfl_xor(hn[i], 1);
        if (!(c & 1)) {
          int b = bg * 16 + q * 4 + i;
          unsigned int pk = (unsigned int)f2bf(hn[i]) | ((unsigned int)f2bf(oth) << 16);
          __hip_atomic_store(
              (unsigned int*)&Hst[(size_t)(dir * 64 + b) * 512 + jn],
              pk, __ATOMIC_RELAXED, __HIP_MEMORY_SCOPE_AGENT);
        }
      }
    }
    arrive(fh_own, tgt + 1);   // h(t) published

    // ---- outp stores AFTER the flag (drain deferred into next poll) ----
    if (w < 2) {
      float* op = dir ? Hb : outp;
#pragma unroll
      for (int i = 0; i < 4; i++) {
        int b = bg * 16 + q * 4 + i;
        op[((size_t)b * TDIM + t) * HDIM + jn] = hn[i];
      }
    }
  }
}

// ---------------- host ----------------

extern "C" void kernel_launch(void* const* d_in, const int* in_sizes, int n_in,
                              void* d_out, int out_size, void* d_ws, size_t ws_size,
                              hipStream_t stream) {
  (void)in_sizes; (void)n_in;
  const float* x  = (const float*)d_in[0];
  const float* h0 = (const float*)d_in[1];
  const float* Wz = (const float*)d_in[2];
  const float* bz = (const float*)d_in[3];
  const float* Wr = (const float*)d_in[4];
  const float* br = (const float*)d_in[5];
  const float* Wh = (const float*)d_in[6];
  const float* bh = (const float*)d_in[7];
  float* outp = (float*)d_out;

  const size_t szG    = (size_t)32768 * 1536 * 2;       // bf16 G
  const size_t szXb   = (size_t)BDIM * TDIM * EDIM * 2;
  const size_t szW    = (size_t)3 * 512 * 512 * 2;
  const size_t szHb   = (size_t)BDIM * TDIM * HDIM * 4;
  const size_t szHst  = (size_t)2 * 64 * 512 * 2;
  const size_t szFl   = 32768;   // 2 x 128 x 128B
  const size_t fixed  = szXb + 2 * szW + szHb + 2 * szHst + szFl + 16384;

  if (ws_size < fixed + szG) {
    sentinel_kern<<<256, 256, 0, stream>>>(outp, out_size);
    return;
  }

  size_t off = 0;
  char* base = (char*)d_ws;
  auto alloc = [&](size_t sz) { char* p = base + off; off = (off + sz + 255) & ~(size_t)255; return p; };
  unsigned short* Gb   = (unsigned short*)alloc(szG);
  unsigned short* xb   = (unsigned short*)alloc(szXb);
  unsigned short* Wxb  = (unsigned short*)alloc(szW);
  unsigned short* Whb  = (unsigned short*)alloc(szW);
  float*          Hbuf = (float*)alloc(szHb);
  unsigned short* Hst  = (unsigned short*)alloc(szHst);
  unsigned short* RHst = (unsigned short*)alloc(szHst);
  unsigned int*   flags= (unsigned int*)alloc(szFl);

  hipMemsetAsync(flags, 0, szFl, stream);
  conv_w<<<(3 * 512 * 1024 + 255) / 256, 256, 0, stream>>>(Wz, Wr, Wh, Wxb, Whb);
  conv_x<<<2048, 256, 0, stream>>>(x, xb, (BDIM * TDIM * EDIM) / 4);
  gru_xproj<<<dim3(256, 12), 256, 0, stream>>>(xb, Wxb, bz, br, bh, Gb);
  gru_persist<<<128, 256, 0, stream>>>(Gb, h0, Hst, RHst, flags, outp, Hbuf, Whb);
  add_out<<<2048, 256, 0, stream>>>(outp, Hbuf, (BDIM * TDIM * HDIM) / 4);
  hipMemcpyAsync(outp + (size_t)BDIM * TDIM * HDIM, h0,
                 (size_t)BDIM * HDIM * sizeof(float), hipMemcpyDeviceToDevice, stream);
}